// Round 10
// baseline (567.373 us; speedup 1.0000x reference)
//
#include <hip/hip_runtime.h>

typedef unsigned int u32;
typedef unsigned short u16;
typedef unsigned long long u64;

typedef __attribute__((ext_vector_type(4))) float f32x4;
typedef __attribute__((ext_vector_type(8))) __bf16 bf16x8;
typedef __attribute__((ext_vector_type(8))) u16 u16x8;
typedef __attribute__((ext_vector_type(4))) u16 u16x4;

#define NB 256
#define ND 512
#define NC 100000
#define NBLK 782               // ceil(NC/128)
#define CAP 131072             // u64 collect entries (1 MB)
#define THRC 0.15f             // collect threshold << neg_th (~0.188)
#define EXP2K 92.33248261689366f   // 64*log2(e)

// ---- ws layout (bytes) ----
#define OFF_EMBN  0            // u16 [256*512] = 262144
#define OFF_TGT   262144       // f32 [256]
#define OFF_SEXP  263168       // f32 [256]
#define OFF_AMAX  264192       // u64 [256] = 2048
#define OFF_SCAL  266240       // u32 [64] {topk, bufcnt, ...}
#define OFF_PART  266496       // f32 [256][800] = 819200
#define OFF_BUF   1085696      // u64 [CAP] = 1048576

__device__ __forceinline__ u32 ordkey(float f) {
  u32 u = __float_as_uint(f);
  return (u & 0x80000000u) ? ~u : (u | 0x80000000u);
}
__device__ __forceinline__ float inv_ordkey(u32 key) {
  u32 u = (key & 0x80000000u) ? (key & 0x7FFFFFFFu) : ~key;
  return __uint_as_float(u);
}
__device__ __forceinline__ u16 f2bf(float x) {  // RNE f32->bf16
  u32 u = __float_as_uint(x);
  return (u16)((u + 0x7FFFu + ((u >> 16) & 1u)) >> 16);
}
__device__ __forceinline__ float bf2f(u16 h) {
  return __uint_as_float(((u32)h) << 16);
}

typedef const u32 __attribute__((address_space(1)))* gcp;
typedef u32 __attribute__((address_space(3)))* lsp;
__device__ __forceinline__ void gload16(const void* g, void* l) {
  __builtin_amdgcn_global_load_lds((gcp)g, (lsp)l, 16, 0, 0);
}

// ---------------- K0: normalize embedding rows -> bf16 + ws clears ----
__global__ void k_prep(const float* __restrict__ emb, u16* __restrict__ embn,
                       u64* __restrict__ amax_g, u32* __restrict__ scal) {
  __shared__ float s[128];
  const int r = blockIdx.x, t = threadIdx.x;
  float4 v = *(const float4*)(emb + r * ND + t * 4);
  s[t] = v.x * v.x + v.y * v.y + v.z * v.z + v.w * v.w;
  const int gidx = r * 128 + t;
  if (gidx < 256) amax_g[gidx] = 0ull;
  else if (gidx < 320) scal[gidx - 256] = 0u;
  __syncthreads();
  for (int st = 64; st > 0; st >>= 1) { if (t < st) s[t] += s[t + st]; __syncthreads(); }
  const float rinv = 1.0f / sqrtf(s[0]);
  u16x4 o = { f2bf(v.x * rinv), f2bf(v.y * rinv), f2bf(v.z * rinv), f2bf(v.w * rinv) };
  *(u16x4*)(embn + r * ND + t * 4) = o;
}

// ---------------- K1: tg[r] = clip(embn[r].bf16(kern[:,lb]) / ||kern[:,lb]||)
__global__ __launch_bounds__(512) void k_tgt(const float* __restrict__ kern,
                                             const u16* __restrict__ embn,
                                             const int* __restrict__ lab,
                                             float* __restrict__ tgtws) {
  __shared__ float sd[512], sq[512];
  const int r = blockIdx.x, t = threadIdx.x;
  const int lb = lab[r];
  const float x = kern[(size_t)t * NC + lb];
  const float xb = bf2f(f2bf(x));                 // same quantization as GEMM B path
  const float a = bf2f(embn[r * ND + t]);
  sd[t] = a * xb; sq[t] = x * x;
  __syncthreads();
  for (int st = 256; st > 0; st >>= 1) {
    if (t < st) { sd[t] += sd[t + st]; sq[t] += sq[t + st]; }
    __syncthreads();
  }
  if (t == 0) {
    float v = sd[0] / sqrtf(sq[0]);
    tgtws[r] = fminf(fmaxf(v, -1.0f), 1.0f);
  }
}

// ---------------- K2: pipelined fused bf16 MFMA GEMM ------------------
// tile M=256 x N=128, BK=32, 16 K-steps, 8 waves (4Mx2N), wave 64x64.
// Double-buffered As/Bs, ONE barrier per step: prefetch(t+1) issued
// before compute(t) (A: global_load_lds fire-and-forget; B: reg loads,
// convert+ds_write after MFMA = T14 split). Swizzle chunk^((row>>1)&3)
// both sides. Epilogue LDS aliases dead Bs -> 48.1KB -> 3 blocks/CU.
__global__ __launch_bounds__(512, 6) void k_gemm(const float* __restrict__ kern,
                                                 const u16* __restrict__ embn,
                                                 const int* __restrict__ lab,
                                                 const float* __restrict__ tgtws,
                                                 u32* __restrict__ scal,
                                                 u64* __restrict__ buf,
                                                 u64* __restrict__ amax_g,
                                                 float* __restrict__ sexp_part) {
  __shared__ char smem[49280];
  u16* Asb[2] = { (u16*)smem, (u16*)(smem + 16384) };          // [256][32] each
  u16* Bsb[2] = { (u16*)(smem + 32768), (u16*)(smem + 40960) };// [128][32] each
  // epilogue aliases (Bs region is dead after the K-loop):
  float* colp = (float*)(smem + 32768);            // [4][128]
  float* sexp_pair = (float*)(smem + 32768 + 2048);// [2][256]
  u64* amax_lds = (u64*)(smem + 32768 + 4096);     // [256]
  u32* swcnt = (u32*)(smem + 32768 + 6144);        // [8]

  const int tid = threadIdx.x;
  const int lane = tid & 63;
  const int w = tid >> 6;
  const int mbase = (w >> 1) * 64, nbase = (w & 1) * 64;
  const int l15 = lane & 15, g = lane >> 4;
  const int cblk = blockIdx.x * 128;

  f32x4 acc[4][4];
  #pragma unroll
  for (int i = 0; i < 4; ++i)
    #pragma unroll
    for (int j = 0; j < 4; ++j) acc[i][j] = (f32x4){0.f, 0.f, 0.f, 0.f};

  // A staging: row = (tid>>2)+i*128, chunk = tid&3; source pre-swizzled.
  const int aswz = ((tid & 3) ^ ((tid >> 3) & 3)) * 8;   // (row>>1)&3 == (tid>>3)&3
  const u16* a_src[2];
  #pragma unroll
  for (int i = 0; i < 2; ++i)
    a_src[i] = embn + (size_t)((tid >> 2) + i * 128) * ND + aswz;
  // wave-uniform LDS dest (lane offset = lane*16B applied by HW)
  const int a_dst = w * 512;                             // u16 units; + i*4096

  // B staging: thread -> col (tid&127), k-oct (tid>>7)
  const int bcol = tid & 127, boct = tid >> 7;
  int gc = cblk + bcol;
  if (gc >= NC) gc = NC - 1;                             // clamp; masked in epilogue
  const float* b_src = kern + (size_t)boct * 8 * NC + gc;
  const int b_dst = bcol * 32 + ((boct ^ ((bcol >> 1) & 3)) * 8);  // u16 units
  float ssq = 0.f;

  // ---- prologue: stage tile 0 ----
  {
    #pragma unroll
    for (int i = 0; i < 2; ++i) gload16(a_src[i], Asb[0] + i * 4096 + a_dst);
    float fb[8];
    #pragma unroll
    for (int j = 0; j < 8; ++j) fb[j] = b_src[(size_t)j * NC];
    u16x8 q;
    #pragma unroll
    for (int j = 0; j < 8; ++j) { ssq += fb[j] * fb[j]; q[j] = f2bf(fb[j]); }
    *(u16x8*)(Bsb[0] + b_dst) = q;
  }
  __syncthreads();

  // ---- main loop: one barrier per K-step ----
  #pragma unroll
  for (int ks = 0; ks < 16; ++ks) {
    const int cur = ks & 1, nxt = cur ^ 1;
    const int k0n = (ks + 1) * 32;
    float fn[8];
    if (ks < 15) {
      // issue next tile's loads early (fly during compute)
      #pragma unroll
      for (int j = 0; j < 8; ++j) fn[j] = b_src[(size_t)(k0n + j) * NC];
      #pragma unroll
      for (int i = 0; i < 2; ++i) gload16(a_src[i] + k0n, Asb[nxt] + i * 4096 + a_dst);
    }
    // compute tile ks from As[cur]/Bs[cur]
    bf16x8 afr[4], bfr[4];
    #pragma unroll
    for (int nf = 0; nf < 4; ++nf) {
      const int n = nbase + nf * 16 + l15;
      bfr[nf] = *(const bf16x8*)(Bsb[cur] + n * 32 + ((g ^ ((n >> 1) & 3)) * 8));
    }
    #pragma unroll
    for (int mf = 0; mf < 4; ++mf) {
      const int m = mbase + mf * 16 + l15;
      afr[mf] = *(const bf16x8*)(Asb[cur] + m * 32 + ((g ^ ((m >> 1) & 3)) * 8));
    }
    #pragma unroll
    for (int mf = 0; mf < 4; ++mf)
      #pragma unroll
      for (int nf = 0; nf < 4; ++nf)
        acc[mf][nf] = __builtin_amdgcn_mfma_f32_16x16x32_bf16(afr[mf], bfr[nf], acc[mf][nf], 0, 0, 0);
    if (ks < 15) {
      // write-late: convert + store B(t+1) after the MFMA block
      u16x8 q;
      #pragma unroll
      for (int j = 0; j < 8; ++j) { ssq += fn[j] * fn[j]; q[j] = f2bf(fn[j]); }
      *(u16x8*)(Bsb[nxt] + b_dst) = q;
    }
    __syncthreads();
  }

  // ---- column ssq (aliased LDS now safe) ----
  colp[boct * 128 + bcol] = ssq;
  if (tid < 256) amax_lds[tid] = 0ull;
  __syncthreads();
  if (tid < 128) {
    float s = (colp[tid] + colp[128 + tid]) + (colp[256 + tid] + colp[384 + tid]);
    colp[tid] = s;
  }
  __syncthreads();

  // ---- fused epilogue: stats straight from accumulators ----
  float cinv[4];
  #pragma unroll
  for (int nf = 0; nf < 4; ++nf) {
    const int nl = nbase + nf * 16 + l15;
    cinv[nf] = ((cblk + nl) < NC) ? (1.0f / sqrtf(colp[nl])) : 0.f;
  }
  u32 cnt_t = 0;
  #pragma unroll
  for (int mf = 0; mf < 4; ++mf) {
    #pragma unroll
    for (int r = 0; r < 4; ++r) {
      const int row = mbase + mf * 16 + g * 4 + r;
      const float tg = tgtws[row];
      const int lb = lab[row];
      float e = 0.f; u64 pk = 0ull;
      #pragma unroll
      for (int nf = 0; nf < 4; ++nf) {
        const int c = cblk + nbase + nf * 16 + l15;
        if (c < NC) {
          float v = acc[mf][nf][r] * cinv[nf];
          v = fminf(fmaxf(v, -1.0f), 1.0f);
          e += exp2f(EXP2K * v);
          const u64 p = ((u64)ordkey(v) << 32) | (u32)(0xFFFFFFFFu - (u32)c);
          if (p > pk) pk = p;
          if (c != lb) {
            if (v > tg) cnt_t++;
            else if (v >= THRC) {
              u32 pos = atomicAdd(&scal[1], 1u);
              if (pos < CAP) buf[pos] = ((u64)ordkey(v) << 32) | (u32)row;
            }
          }
        }
      }
      #pragma unroll
      for (int m = 1; m < 16; m <<= 1) {
        e += __shfl_xor(e, m, 64);
        u64 o = __shfl_xor(pk, m, 64);
        if (o > pk) pk = o;
      }
      if (l15 == 0) {
        sexp_pair[(w & 1) * 256 + row] = e;    // each slot written exactly once
        atomicMax(&amax_lds[row], pk);         // integer max: order-independent
      }
    }
  }
  #pragma unroll
  for (int m = 1; m < 64; m <<= 1) cnt_t += __shfl_xor(cnt_t, m, 64);
  if (lane == 0) swcnt[w] = cnt_t;
  __syncthreads();
  if (tid == 0) {
    u32 s = 0;
    #pragma unroll
    for (int i = 0; i < 8; ++i) s += swcnt[i];
    atomicAdd(&scal[0], s);
  }
  if (tid < 256) {
    sexp_part[(size_t)tid * 800 + blockIdx.x] = sexp_pair[tid] + sexp_pair[256 + tid];
    atomicMax(&amax_g[tid], amax_lds[tid]);
  }
}

// ---------------- K3: deterministic per-row sexp reduction ------------
__global__ void k_reduce(const float* __restrict__ part, float* __restrict__ sexpws) {
  __shared__ float s[256];
  const int r = blockIdx.x, t = threadIdx.x;
  float a = 0.f;
  for (int b = t; b < NBLK; b += 256) a += part[(size_t)r * 800 + b];
  s[t] = a;
  __syncthreads();
  for (int st = 128; st > 0; st >>= 1) { if (t < st) s[t] += s[t + st]; __syncthreads(); }
  if (t == 0) sexpws[r] = s[0];
}

// ---------------- K4: finisher (1 block): select th + stats + loss ----
__global__ __launch_bounds__(1024) void k_finish(const u64* __restrict__ buf,
                                                 const u32* __restrict__ scal,
                                                 const int* __restrict__ lab,
                                                 const float* __restrict__ tgtws,
                                                 const float* __restrict__ sexpws,
                                                 const u64* __restrict__ amax_g,
                                                 float* __restrict__ out) {
  __shared__ u32 hist[4096];
  __shared__ u32 s[1024], cs[1024];
  __shared__ u32 sb1, sr1, sb2, sr2, sthkey, lcnt;
  __shared__ u64 lbuf[512];
  __shared__ float rl[256], ra[256];
  const int tid = threadIdx.x;
  const int n = (int)min(scal[1], (u32)CAP);
  const int topk = (int)scal[0];
  int a = 25599744 - topk; if (a < 0) a = 0;               // B*(C-1)
  int k = (int)ceilf((1.0f / 99999.0f) * (float)a);        // mirror ref f32 math
  if (k < 1) k = 1;

  if (tid == 0) { sb1 = 0; sr1 = 1; sb2 = 0; sr2 = 1; lcnt = 0; }
  // ---- level 1: key bits 31..20 ----
  for (int i = tid; i < 4096; i += 1024) hist[i] = 0;
  __syncthreads();
  for (int i = tid; i < n; i += 1024) atomicAdd(&hist[(u32)(buf[i] >> 52)], 1u);
  __syncthreads();
  {
    u32 h[4]; u32 c = 0;
    #pragma unroll
    for (int j = 0; j < 4; ++j) { h[j] = hist[tid * 4 + j]; c += h[j]; }
    cs[tid] = c; s[tid] = c;
    __syncthreads();
    for (int off = 1; off < 1024; off <<= 1) {
      u32 v = (tid + off < 1024) ? s[tid + off] : 0u;
      __syncthreads(); s[tid] += v; __syncthreads();
    }
    u32 incl = s[tid], excl = incl - cs[tid];
    if ((int)excl < k && (int)incl >= k) {
      u32 cum = excl;
      for (int j = 3; j >= 0; --j) {
        cum += h[j];
        if ((int)cum >= k) { sb1 = tid * 4 + j; sr1 = (u32)k - (cum - h[j]); break; }
      }
    }
  }
  __syncthreads();
  const u32 b1 = sb1, r1 = sr1;
  // ---- level 2: key bits 19..8 ----
  for (int i = tid; i < 4096; i += 1024) hist[i] = 0;
  __syncthreads();
  for (int i = tid; i < n; i += 1024) {
    u32 key = (u32)(buf[i] >> 32);
    if ((key >> 20) == b1) atomicAdd(&hist[(key >> 8) & 4095u], 1u);
  }
  __syncthreads();
  {
    u32 h[4]; u32 c = 0;
    #pragma unroll
    for (int j = 0; j < 4; ++j) { h[j] = hist[tid * 4 + j]; c += h[j]; }
    cs[tid] = c; s[tid] = c;
    __syncthreads();
    for (int off = 1; off < 1024; off <<= 1) {
      u32 v = (tid + off < 1024) ? s[tid + off] : 0u;
      __syncthreads(); s[tid] += v; __syncthreads();
    }
    u32 incl = s[tid], excl = incl - cs[tid];
    if (excl < r1 && incl >= r1) {
      u32 cum = excl;
      for (int j = 3; j >= 0; --j) {
        cum += h[j];
        if (cum >= r1) { sb2 = tid * 4 + j; sr2 = r1 - (cum - h[j]); break; }
      }
    }
  }
  __syncthreads();
  const u32 b2 = sb2, r2 = sr2;
  // ---- level 3: key bits 7..0 ----
  for (int i = tid; i < 256; i += 1024) hist[i] = 0;
  __syncthreads();
  const u32 pfx = (b1 << 12) | b2;
  for (int i = tid; i < n; i += 1024) {
    u32 key = (u32)(buf[i] >> 32);
    if ((key >> 8) == pfx) atomicAdd(&hist[key & 255u], 1u);
  }
  __syncthreads();
  if (tid == 0) {
    u32 cum = 0, b3 = 0;
    for (int j = 255; j >= 0; --j) { cum += hist[j]; if (cum >= r2) { b3 = (u32)j; break; } }
    sthkey = (b1 << 20) | (b2 << 8) | b3;
  }
  __syncthreads();
  const u32 thk = sthkey;
  // ---- collect strictly-greater entries (k-1 < 512 of them) ----
  for (int i = tid; i < n; i += 1024) {
    u64 e = buf[i];
    if ((u32)(e >> 32) > thk) { u32 p = atomicAdd(&lcnt, 1u); if (p < 512) lbuf[p] = e; }
  }
  __syncthreads();
  const int m = (int)min(lcnt, 512u);
  if (tid < 256) {
    const int r = tid;
    int cnt = 0; float ssq = 0.f;
    for (int j = 0; j < m; ++j) {
      u64 e = lbuf[j];
      if ((u32)(e & 0xFFFFFFFFu) == (u32)r) {
        float v = inv_ordkey((u32)(e >> 32));
        cnt++; ssq += v * v;
      }
    }
    const float tg = tgtws[r];
    const float times = fmaxf((float)cnt, 1.0f);
    const float nm = ssq / times;
    const float tgm = (tg - 0.4f) - (1.0f + tg) * nm;
    const float sexp = sexpws[r] - exp2f(EXP2K * tg) + exp2f(EXP2K * tgm);
    rl[r] = logf(sexp) - 64.0f * tgm;
    const u32 acol = 0xFFFFFFFFu - (u32)(amax_g[r] & 0xFFFFFFFFu);
    ra[r] = (acol == (u32)lab[r]) ? 1.0f : 0.0f;
  }
  __syncthreads();
  for (int st = 128; st > 0; st >>= 1) {
    if (tid < st) { rl[tid] += rl[tid + st]; ra[tid] += ra[tid + st]; }
    __syncthreads();
  }
  if (tid == 0) { out[0] = rl[0] * (1.0f / 256.0f); out[1] = ra[0] * (1.0f / 256.0f); }
}

extern "C" void kernel_launch(void* const* d_in, const int* in_sizes, int n_in,
                              void* d_out, int out_size, void* d_ws, size_t ws_size,
                              hipStream_t stream) {
  const float* emb = (const float*)d_in[0];
  const int* lab = (const int*)d_in[1];
  const float* kern = (const float*)d_in[2];
  float* out = (float*)d_out;
  char* ws = (char*)d_ws;

  u16* embn = (u16*)(ws + OFF_EMBN);
  float* tgtws = (float*)(ws + OFF_TGT);
  float* sexpws = (float*)(ws + OFF_SEXP);
  u64* amax_g = (u64*)(ws + OFF_AMAX);
  u32* scal = (u32*)(ws + OFF_SCAL);   // [0]=topk [1]=bufcnt
  float* part = (float*)(ws + OFF_PART);
  u64* buf = (u64*)(ws + OFF_BUF);

  k_prep<<<NB, 128, 0, stream>>>(emb, embn, amax_g, scal);
  k_tgt<<<NB, 512, 0, stream>>>(kern, embn, lab, tgtws);
  k_gemm<<<NBLK, 512, 0, stream>>>(kern, embn, lab, tgtws, scal, buf, amax_g, part);
  k_reduce<<<NB, 256, 0, stream>>>(part, sexpws);
  k_finish<<<1, 1024, 0, stream>>>(buf, scal, lab, tgtws, sexpws, amax_g, out);
}

// Round 11
// 121.754 us; speedup vs baseline: 4.6600x; 4.6600x over previous
//
#include <hip/hip_runtime.h>

typedef unsigned int u32;
typedef unsigned short u16;
typedef unsigned long long u64;

typedef __attribute__((ext_vector_type(4))) float f32x4;
typedef __attribute__((ext_vector_type(8))) __bf16 bf16x8;
typedef __attribute__((ext_vector_type(8))) u16 u16x8;
typedef __attribute__((ext_vector_type(4))) u16 u16x4;

#define NB 256
#define ND 512
#define NC 100000
#define NBLK 782               // ceil(NC/128)
#define CAP 131072             // u64 collect entries (1 MB)
#define THRC 0.15f             // collect threshold << neg_th (~0.188)
#define EXP2K 92.33248261689366f   // 64*log2(e)

// ---- ws layout (bytes) ----
#define OFF_EMBN  0            // u16 [256*512] = 262144
#define OFF_TGT   262144       // f32 [256]
#define OFF_SEXP  263168       // f32 [256]
#define OFF_AMAX  264192       // u64 [256] = 2048
#define OFF_SCAL  266240       // u32 [64] {topk, bufcnt, ...}
#define OFF_PART  266496       // f32 [256][800] = 819200
#define OFF_BUF   1085696      // u64 [CAP] = 1048576

__device__ __forceinline__ u32 ordkey(float f) {
  u32 u = __float_as_uint(f);
  return (u & 0x80000000u) ? ~u : (u | 0x80000000u);
}
__device__ __forceinline__ float inv_ordkey(u32 key) {
  u32 u = (key & 0x80000000u) ? (key & 0x7FFFFFFFu) : ~key;
  return __uint_as_float(u);
}
__device__ __forceinline__ u16 f2bf(float x) {  // RNE f32->bf16
  u32 u = __float_as_uint(x);
  return (u16)((u + 0x7FFFu + ((u >> 16) & 1u)) >> 16);
}
__device__ __forceinline__ float bf2f(u16 h) {
  return __uint_as_float(((u32)h) << 16);
}

typedef const u32 __attribute__((address_space(1)))* gcp;
typedef u32 __attribute__((address_space(3)))* lsp;
__device__ __forceinline__ void gload16(const void* g, void* l) {
  __builtin_amdgcn_global_load_lds((gcp)g, (lsp)l, 16, 0, 0);
}

// ---------------- K0: normalize embedding rows -> bf16 + ws clears ----
__global__ void k_prep(const float* __restrict__ emb, u16* __restrict__ embn,
                       u64* __restrict__ amax_g, u32* __restrict__ scal) {
  __shared__ float s[128];
  const int r = blockIdx.x, t = threadIdx.x;
  float4 v = *(const float4*)(emb + r * ND + t * 4);
  s[t] = v.x * v.x + v.y * v.y + v.z * v.z + v.w * v.w;
  const int gidx = r * 128 + t;
  if (gidx < 256) amax_g[gidx] = 0ull;
  else if (gidx < 320) scal[gidx - 256] = 0u;
  __syncthreads();
  for (int st = 64; st > 0; st >>= 1) { if (t < st) s[t] += s[t + st]; __syncthreads(); }
  const float rinv = 1.0f / sqrtf(s[0]);
  u16x4 o = { f2bf(v.x * rinv), f2bf(v.y * rinv), f2bf(v.z * rinv), f2bf(v.w * rinv) };
  *(u16x4*)(embn + r * ND + t * 4) = o;
}

// ---------------- K1: tg[r] = clip(embn[r].bf16(kern[:,lb]) / ||kern[:,lb]||)
__global__ __launch_bounds__(512) void k_tgt(const float* __restrict__ kern,
                                             const u16* __restrict__ embn,
                                             const int* __restrict__ lab,
                                             float* __restrict__ tgtws) {
  __shared__ float sd[512], sq[512];
  const int r = blockIdx.x, t = threadIdx.x;
  const int lb = lab[r];
  const float x = kern[(size_t)t * NC + lb];
  const float xb = bf2f(f2bf(x));                 // same quantization as GEMM B path
  const float a = bf2f(embn[r * ND + t]);
  sd[t] = a * xb; sq[t] = x * x;
  __syncthreads();
  for (int st = 256; st > 0; st >>= 1) {
    if (t < st) { sd[t] += sd[t + st]; sq[t] += sq[t + st]; }
    __syncthreads();
  }
  if (t == 0) {
    float v = sd[0] / sqrtf(sq[0]);
    tgtws[r] = fminf(fmaxf(v, -1.0f), 1.0f);
  }
}

// ---------------- K2: pipelined fused bf16 MFMA GEMM ------------------
// tile M=256 x N=128, BK=32, 16 K-steps, 8 waves (4Mx2N), wave 64x64.
// Double-buffered As/Bs, ONE barrier per step. launch_bounds (512,4):
// 128 VGPR/thread budget -- R9's (512,6) capped at ~85 and spilled acc
// to scratch (987 MB scratch writes, 552 us). Structure otherwise as R9.
__global__ __launch_bounds__(512, 4) void k_gemm(const float* __restrict__ kern,
                                                 const u16* __restrict__ embn,
                                                 const int* __restrict__ lab,
                                                 const float* __restrict__ tgtws,
                                                 u32* __restrict__ scal,
                                                 u64* __restrict__ buf,
                                                 u64* __restrict__ amax_g,
                                                 float* __restrict__ sexp_part) {
  __shared__ char smem[49280];
  u16* Asb[2] = { (u16*)smem, (u16*)(smem + 16384) };          // [256][32] each
  u16* Bsb[2] = { (u16*)(smem + 32768), (u16*)(smem + 40960) };// [128][32] each
  // epilogue aliases (Bs region is dead after the K-loop):
  float* colp = (float*)(smem + 32768);            // [4][128]
  float* sexp_pair = (float*)(smem + 32768 + 2048);// [2][256]
  u64* amax_lds = (u64*)(smem + 32768 + 4096);     // [256]
  u32* swcnt = (u32*)(smem + 32768 + 6144);        // [8]

  const int tid = threadIdx.x;
  const int lane = tid & 63;
  const int w = tid >> 6;
  const int mbase = (w >> 1) * 64, nbase = (w & 1) * 64;
  const int l15 = lane & 15, g = lane >> 4;
  const int cblk = blockIdx.x * 128;

  f32x4 acc[4][4];
  #pragma unroll
  for (int i = 0; i < 4; ++i)
    #pragma unroll
    for (int j = 0; j < 4; ++j) acc[i][j] = (f32x4){0.f, 0.f, 0.f, 0.f};

  // A staging: row = (tid>>2)+i*128, chunk = tid&3; source pre-swizzled.
  const int aswz = ((tid & 3) ^ ((tid >> 3) & 3)) * 8;   // (row>>1)&3 == (tid>>3)&3
  const u16* a_src[2];
  #pragma unroll
  for (int i = 0; i < 2; ++i)
    a_src[i] = embn + (size_t)((tid >> 2) + i * 128) * ND + aswz;
  // wave-uniform LDS dest (lane offset = lane*16B applied by HW)
  const int a_dst = w * 512;                             // u16 units; + i*4096

  // B staging: thread -> col (tid&127), k-oct (tid>>7)
  const int bcol = tid & 127, boct = tid >> 7;
  int gc = cblk + bcol;
  if (gc >= NC) gc = NC - 1;                             // clamp; masked in epilogue
  const float* b_src = kern + (size_t)boct * 8 * NC + gc;
  const int b_dst = bcol * 32 + ((boct ^ ((bcol >> 1) & 3)) * 8);  // u16 units
  float ssq = 0.f;

  // ---- prologue: stage tile 0 ----
  {
    #pragma unroll
    for (int i = 0; i < 2; ++i) gload16(a_src[i], Asb[0] + i * 4096 + a_dst);
    float fb[8];
    #pragma unroll
    for (int j = 0; j < 8; ++j) fb[j] = b_src[(size_t)j * NC];
    u16x8 q;
    #pragma unroll
    for (int j = 0; j < 8; ++j) { ssq += fb[j] * fb[j]; q[j] = f2bf(fb[j]); }
    *(u16x8*)(Bsb[0] + b_dst) = q;
  }
  __syncthreads();

  // ---- main loop: one barrier per K-step ----
  #pragma unroll
  for (int ks = 0; ks < 16; ++ks) {
    const int cur = ks & 1, nxt = cur ^ 1;
    const int k0n = (ks + 1) * 32;
    float fn[8];
    if (ks < 15) {
      // issue next tile's loads early (fly during compute)
      #pragma unroll
      for (int j = 0; j < 8; ++j) fn[j] = b_src[(size_t)(k0n + j) * NC];
      #pragma unroll
      for (int i = 0; i < 2; ++i) gload16(a_src[i] + k0n, Asb[nxt] + i * 4096 + a_dst);
    }
    // compute tile ks from As[cur]/Bs[cur]
    bf16x8 afr[4], bfr[4];
    #pragma unroll
    for (int nf = 0; nf < 4; ++nf) {
      const int n = nbase + nf * 16 + l15;
      bfr[nf] = *(const bf16x8*)(Bsb[cur] + n * 32 + ((g ^ ((n >> 1) & 3)) * 8));
    }
    #pragma unroll
    for (int mf = 0; mf < 4; ++mf) {
      const int m = mbase + mf * 16 + l15;
      afr[mf] = *(const bf16x8*)(Asb[cur] + m * 32 + ((g ^ ((m >> 1) & 3)) * 8));
    }
    #pragma unroll
    for (int mf = 0; mf < 4; ++mf)
      #pragma unroll
      for (int nf = 0; nf < 4; ++nf)
        acc[mf][nf] = __builtin_amdgcn_mfma_f32_16x16x32_bf16(afr[mf], bfr[nf], acc[mf][nf], 0, 0, 0);
    if (ks < 15) {
      // write-late: convert + store B(t+1) after the MFMA block
      u16x8 q;
      #pragma unroll
      for (int j = 0; j < 8; ++j) { ssq += fn[j] * fn[j]; q[j] = f2bf(fn[j]); }
      *(u16x8*)(Bsb[nxt] + b_dst) = q;
    }
    __syncthreads();
  }

  // ---- column ssq (aliased LDS now safe) ----
  colp[boct * 128 + bcol] = ssq;
  if (tid < 256) amax_lds[tid] = 0ull;
  __syncthreads();
  if (tid < 128) {
    float s = (colp[tid] + colp[128 + tid]) + (colp[256 + tid] + colp[384 + tid]);
    colp[tid] = s;
  }
  __syncthreads();

  // ---- fused epilogue: stats straight from accumulators ----
  float cinv[4];
  #pragma unroll
  for (int nf = 0; nf < 4; ++nf) {
    const int nl = nbase + nf * 16 + l15;
    cinv[nf] = ((cblk + nl) < NC) ? (1.0f / sqrtf(colp[nl])) : 0.f;
  }
  u32 cnt_t = 0;
  #pragma unroll
  for (int mf = 0; mf < 4; ++mf) {
    #pragma unroll
    for (int r = 0; r < 4; ++r) {
      const int row = mbase + mf * 16 + g * 4 + r;
      const float tg = tgtws[row];
      const int lb = lab[row];
      float e = 0.f; u64 pk = 0ull;
      #pragma unroll
      for (int nf = 0; nf < 4; ++nf) {
        const int c = cblk + nbase + nf * 16 + l15;
        if (c < NC) {
          float v = acc[mf][nf][r] * cinv[nf];
          v = fminf(fmaxf(v, -1.0f), 1.0f);
          e += exp2f(EXP2K * v);
          const u64 p = ((u64)ordkey(v) << 32) | (u32)(0xFFFFFFFFu - (u32)c);
          if (p > pk) pk = p;
          if (c != lb) {
            if (v > tg) cnt_t++;
            else if (v >= THRC) {
              u32 pos = atomicAdd(&scal[1], 1u);
              if (pos < CAP) buf[pos] = ((u64)ordkey(v) << 32) | (u32)row;
            }
          }
        }
      }
      #pragma unroll
      for (int m = 1; m < 16; m <<= 1) {
        e += __shfl_xor(e, m, 64);
        u64 o = __shfl_xor(pk, m, 64);
        if (o > pk) pk = o;
      }
      if (l15 == 0) {
        sexp_pair[(w & 1) * 256 + row] = e;    // each slot written exactly once
        atomicMax(&amax_lds[row], pk);         // integer max: order-independent
      }
    }
  }
  #pragma unroll
  for (int m = 1; m < 64; m <<= 1) cnt_t += __shfl_xor(cnt_t, m, 64);
  if (lane == 0) swcnt[w] = cnt_t;
  __syncthreads();
  if (tid == 0) {
    u32 s = 0;
    #pragma unroll
    for (int i = 0; i < 8; ++i) s += swcnt[i];
    atomicAdd(&scal[0], s);
  }
  if (tid < 256) {
    sexp_part[(size_t)tid * 800 + blockIdx.x] = sexp_pair[tid] + sexp_pair[256 + tid];
    atomicMax(&amax_g[tid], amax_lds[tid]);
  }
}

// ---------------- K3: deterministic per-row sexp reduction ------------
__global__ void k_reduce(const float* __restrict__ part, float* __restrict__ sexpws) {
  __shared__ float s[256];
  const int r = blockIdx.x, t = threadIdx.x;
  float a = 0.f;
  for (int b = t; b < NBLK; b += 256) a += part[(size_t)r * 800 + b];
  s[t] = a;
  __syncthreads();
  for (int st = 128; st > 0; st >>= 1) { if (t < st) s[t] += s[t + st]; __syncthreads(); }
  if (t == 0) sexpws[r] = s[0];
}

// ---------------- K4: finisher (1 block): select th + stats + loss ----
__global__ __launch_bounds__(1024) void k_finish(const u64* __restrict__ buf,
                                                 const u32* __restrict__ scal,
                                                 const int* __restrict__ lab,
                                                 const float* __restrict__ tgtws,
                                                 const float* __restrict__ sexpws,
                                                 const u64* __restrict__ amax_g,
                                                 float* __restrict__ out) {
  __shared__ u32 hist[4096];
  __shared__ u32 s[1024], cs[1024];
  __shared__ u32 sb1, sr1, sb2, sr2, sthkey, lcnt;
  __shared__ u64 lbuf[512];
  __shared__ float rl[256], ra[256];
  const int tid = threadIdx.x;
  const int n = (int)min(scal[1], (u32)CAP);
  const int topk = (int)scal[0];
  int a = 25599744 - topk; if (a < 0) a = 0;               // B*(C-1)
  int k = (int)ceilf((1.0f / 99999.0f) * (float)a);        // mirror ref f32 math
  if (k < 1) k = 1;

  if (tid == 0) { sb1 = 0; sr1 = 1; sb2 = 0; sr2 = 1; lcnt = 0; }
  // ---- level 1: key bits 31..20 ----
  for (int i = tid; i < 4096; i += 1024) hist[i] = 0;
  __syncthreads();
  for (int i = tid; i < n; i += 1024) atomicAdd(&hist[(u32)(buf[i] >> 52)], 1u);
  __syncthreads();
  {
    u32 h[4]; u32 c = 0;
    #pragma unroll
    for (int j = 0; j < 4; ++j) { h[j] = hist[tid * 4 + j]; c += h[j]; }
    cs[tid] = c; s[tid] = c;
    __syncthreads();
    for (int off = 1; off < 1024; off <<= 1) {
      u32 v = (tid + off < 1024) ? s[tid + off] : 0u;
      __syncthreads(); s[tid] += v; __syncthreads();
    }
    u32 incl = s[tid], excl = incl - cs[tid];
    if ((int)excl < k && (int)incl >= k) {
      u32 cum = excl;
      for (int j = 3; j >= 0; --j) {
        cum += h[j];
        if ((int)cum >= k) { sb1 = tid * 4 + j; sr1 = (u32)k - (cum - h[j]); break; }
      }
    }
  }
  __syncthreads();
  const u32 b1 = sb1, r1 = sr1;
  // ---- level 2: key bits 19..8 ----
  for (int i = tid; i < 4096; i += 1024) hist[i] = 0;
  __syncthreads();
  for (int i = tid; i < n; i += 1024) {
    u32 key = (u32)(buf[i] >> 32);
    if ((key >> 20) == b1) atomicAdd(&hist[(key >> 8) & 4095u], 1u);
  }
  __syncthreads();
  {
    u32 h[4]; u32 c = 0;
    #pragma unroll
    for (int j = 0; j < 4; ++j) { h[j] = hist[tid * 4 + j]; c += h[j]; }
    cs[tid] = c; s[tid] = c;
    __syncthreads();
    for (int off = 1; off < 1024; off <<= 1) {
      u32 v = (tid + off < 1024) ? s[tid + off] : 0u;
      __syncthreads(); s[tid] += v; __syncthreads();
    }
    u32 incl = s[tid], excl = incl - cs[tid];
    if (excl < r1 && incl >= r1) {
      u32 cum = excl;
      for (int j = 3; j >= 0; --j) {
        cum += h[j];
        if (cum >= r1) { sb2 = tid * 4 + j; sr2 = r1 - (cum - h[j]); break; }
      }
    }
  }
  __syncthreads();
  const u32 b2 = sb2, r2 = sr2;
  // ---- level 3: key bits 7..0 ----
  for (int i = tid; i < 256; i += 1024) hist[i] = 0;
  __syncthreads();
  const u32 pfx = (b1 << 12) | b2;
  for (int i = tid; i < n; i += 1024) {
    u32 key = (u32)(buf[i] >> 32);
    if ((key >> 8) == pfx) atomicAdd(&hist[key & 255u], 1u);
  }
  __syncthreads();
  if (tid == 0) {
    u32 cum = 0, b3 = 0;
    for (int j = 255; j >= 0; --j) { cum += hist[j]; if (cum >= r2) { b3 = (u32)j; break; } }
    sthkey = (b1 << 20) | (b2 << 8) | b3;
  }
  __syncthreads();
  const u32 thk = sthkey;
  // ---- collect strictly-greater entries (k-1 < 512 of them) ----
  for (int i = tid; i < n; i += 1024) {
    u64 e = buf[i];
    if ((u32)(e >> 32) > thk) { u32 p = atomicAdd(&lcnt, 1u); if (p < 512) lbuf[p] = e; }
  }
  __syncthreads();
  const int m = (int)min(lcnt, 512u);
  if (tid < 256) {
    const int r = tid;
    int cnt = 0; float ssq = 0.f;
    for (int j = 0; j < m; ++j) {
      u64 e = lbuf[j];
      if ((u32)(e & 0xFFFFFFFFu) == (u32)r) {
        float v = inv_ordkey((u32)(e >> 32));
        cnt++; ssq += v * v;
      }
    }
    const float tg = tgtws[r];
    const float times = fmaxf((float)cnt, 1.0f);
    const float nm = ssq / times;
    const float tgm = (tg - 0.4f) - (1.0f + tg) * nm;
    const float sexp = sexpws[r] - exp2f(EXP2K * tg) + exp2f(EXP2K * tgm);
    rl[r] = logf(sexp) - 64.0f * tgm;
    const u32 acol = 0xFFFFFFFFu - (u32)(amax_g[r] & 0xFFFFFFFFu);
    ra[r] = (acol == (u32)lab[r]) ? 1.0f : 0.0f;
  }
  __syncthreads();
  for (int st = 128; st > 0; st >>= 1) {
    if (tid < st) { rl[tid] += rl[tid + st]; ra[tid] += ra[tid + st]; }
    __syncthreads();
  }
  if (tid == 0) { out[0] = rl[0] * (1.0f / 256.0f); out[1] = ra[0] * (1.0f / 256.0f); }
}

extern "C" void kernel_launch(void* const* d_in, const int* in_sizes, int n_in,
                              void* d_out, int out_size, void* d_ws, size_t ws_size,
                              hipStream_t stream) {
  const float* emb = (const float*)d_in[0];
  const int* lab = (const int*)d_in[1];
  const float* kern = (const float*)d_in[2];
  float* out = (float*)d_out;
  char* ws = (char*)d_ws;

  u16* embn = (u16*)(ws + OFF_EMBN);
  float* tgtws = (float*)(ws + OFF_TGT);
  float* sexpws = (float*)(ws + OFF_SEXP);
  u64* amax_g = (u64*)(ws + OFF_AMAX);
  u32* scal = (u32*)(ws + OFF_SCAL);   // [0]=topk [1]=bufcnt
  float* part = (float*)(ws + OFF_PART);
  u64* buf = (u64*)(ws + OFF_BUF);

  k_prep<<<NB, 128, 0, stream>>>(emb, embn, amax_g, scal);
  k_tgt<<<NB, 512, 0, stream>>>(kern, embn, lab, tgtws);
  k_gemm<<<NBLK, 512, 0, stream>>>(kern, embn, lab, tgtws, scal, buf, amax_g, part);
  k_reduce<<<NB, 256, 0, stream>>>(part, sexpws);
  k_finish<<<1, 1024, 0, stream>>>(buf, scal, lab, tgtws, sexpws, amax_g, out);
}

// Round 12
// 116.504 us; speedup vs baseline: 4.8700x; 1.0451x over previous
//
#include <hip/hip_runtime.h>

typedef unsigned int u32;
typedef unsigned short u16;
typedef unsigned long long u64;

typedef __attribute__((ext_vector_type(4))) float f32x4;
typedef __attribute__((ext_vector_type(8))) __bf16 bf16x8;
typedef __attribute__((ext_vector_type(8))) u16 u16x8;
typedef __attribute__((ext_vector_type(4))) u16 u16x4;

#define NB 256
#define ND 512
#define NC 100000
#define NBLK 782               // ceil(NC/128)
#define CAP 131072             // u64 collect entries (1 MB)
#define THRC 0.15f             // collect threshold << neg_th (~0.188)
#define EXP2K 92.33248261689366f   // 64*log2(e)

// ---- ws layout (bytes) ----
#define OFF_EMBN  0            // u16 [256*512] = 262144
#define OFF_TGT   262144       // f32 [256]
#define OFF_SEXP  263168       // f32 [256]
#define OFF_AMAX  264192       // u64 [256] = 2048
#define OFF_SCAL  266240       // u32 [64] {topk, bufcnt, ...}
#define OFF_PART  266496       // f32 [256][800] = 819200
#define OFF_BUF   1085696      // u64 [CAP] = 1048576

__device__ __forceinline__ u32 ordkey(float f) {
  u32 u = __float_as_uint(f);
  return (u & 0x80000000u) ? ~u : (u | 0x80000000u);
}
__device__ __forceinline__ float inv_ordkey(u32 key) {
  u32 u = (key & 0x80000000u) ? (key & 0x7FFFFFFFu) : ~key;
  return __uint_as_float(u);
}
__device__ __forceinline__ u16 f2bf(float x) {  // RNE f32->bf16
  u32 u = __float_as_uint(x);
  return (u16)((u + 0x7FFFu + ((u >> 16) & 1u)) >> 16);
}
__device__ __forceinline__ float bf2f(u16 h) {
  return __uint_as_float(((u32)h) << 16);
}
// B-LDS chunk swizzle: 8 distinct values over both lane patterns
__device__ __forceinline__ int bswz(int n) {
  return (n & 7) ^ ((n >> 3) & 7);
}

typedef const u32 __attribute__((address_space(1)))* gcp;
typedef u32 __attribute__((address_space(3)))* lsp;
__device__ __forceinline__ void gload16(const void* g, void* l) {
  __builtin_amdgcn_global_load_lds((gcp)g, (lsp)l, 16, 0, 0);
}

// ---------------- K0: normalize embedding rows -> bf16 + ws clears ----
__global__ void k_prep(const float* __restrict__ emb, u16* __restrict__ embn,
                       u64* __restrict__ amax_g, u32* __restrict__ scal) {
  __shared__ float s[128];
  const int r = blockIdx.x, t = threadIdx.x;
  float4 v = *(const float4*)(emb + r * ND + t * 4);
  s[t] = v.x * v.x + v.y * v.y + v.z * v.z + v.w * v.w;
  const int gidx = r * 128 + t;
  if (gidx < 256) amax_g[gidx] = 0ull;
  else if (gidx < 320) scal[gidx - 256] = 0u;
  __syncthreads();
  for (int st = 64; st > 0; st >>= 1) { if (t < st) s[t] += s[t + st]; __syncthreads(); }
  const float rinv = 1.0f / sqrtf(s[0]);
  u16x4 o = { f2bf(v.x * rinv), f2bf(v.y * rinv), f2bf(v.z * rinv), f2bf(v.w * rinv) };
  *(u16x4*)(embn + r * ND + t * 4) = o;
}

// ---------------- K1: tg[r] = clip(embn[r].bf16(kern[:,lb]) / ||kern[:,lb]||)
__global__ __launch_bounds__(512) void k_tgt(const float* __restrict__ kern,
                                             const u16* __restrict__ embn,
                                             const int* __restrict__ lab,
                                             float* __restrict__ tgtws) {
  __shared__ float sd[512], sq[512];
  const int r = blockIdx.x, t = threadIdx.x;
  const int lb = lab[r];
  const float x = kern[(size_t)t * NC + lb];
  const float xb = bf2f(f2bf(x));                 // same quantization as GEMM B path
  const float a = bf2f(embn[r * ND + t]);
  sd[t] = a * xb; sq[t] = x * x;
  __syncthreads();
  for (int st = 256; st > 0; st >>= 1) {
    if (t < st) { sd[t] += sd[t + st]; sq[t] += sq[t + st]; }
    __syncthreads();
  }
  if (t == 0) {
    float v = sd[0] / sqrtf(sq[0]);
    tgtws[r] = fminf(fmaxf(v, -1.0f), 1.0f);
  }
}

// ---------------- K2: FUSED bf16 MFMA GEMM (R8 structure, best) -------
// tile M=256 x N=128, BK=64, 8 waves (4Mx2N), wave-tile 64x64, acc[4][4].
// A: embn bf16 via global_load_lds(16B), XOR-preswizzled source.
// B: 8x float2 fp32 loads -> in-register transpose -> f2bf -> 2x
//    ds_write_b128 into Bs[n][64] chunk-swizzled -> b128 fragment reads.
// NEW (R12): chunked-XCD payload swizzle -- each XCD owns ~98 CONSECUTIVE
// column stripes so its HBM request stream clusters per k-row (DRAM
// page-locality test). Bijective remap: b%8 -> class, b/8 -> index.
__global__ __launch_bounds__(512, 4) void k_gemm(const float* __restrict__ kern,
                                                 const u16* __restrict__ embn,
                                                 const int* __restrict__ lab,
                                                 const float* __restrict__ tgtws,
                                                 u32* __restrict__ scal,
                                                 u64* __restrict__ buf,
                                                 u64* __restrict__ amax_g,
                                                 float* __restrict__ sexp_part) {
  __shared__ u16 As[256 * 64];        // [m][k] linear (source-swizzled), rows 128B
  __shared__ u16 Bs[128 * 64];        // [n][k] chunk-swizzled, rows 128B
  __shared__ float colp[8][128];      // column ssq partials (k-oct rows)
  __shared__ float sexp_pair[2][256]; // per n-half partials (deterministic)
  __shared__ u64 amax_lds[256];
  __shared__ u32 swcnt[8];
  const int tid = threadIdx.x;
  const int lane = tid & 63;
  const int w = tid >> 6;
  const int mbase = (w >> 1) * 64, nbase = (w & 1) * 64;
  const int l15 = lane & 15, g = lane >> 4;
  // chunked-XCD swizzle: payload stripe p; XCD r8 = bid%8 owns ~98
  // consecutive stripes. classes 0..5: 98 each, 6..7: 97 each (bijective).
  const int bid = blockIdx.x;
  const int r8 = bid & 7, i8 = bid >> 3;
  const int p = (r8 < 6 ? r8 * 98 : 588 + (r8 - 6) * 97) + i8;
  const int cblk = p * 128;

  if (tid < 256) amax_lds[tid] = 0ull;

  f32x4 acc[4][4];
  #pragma unroll
  for (int i = 0; i < 4; ++i)
    #pragma unroll
    for (int j = 0; j < 4; ++j) acc[i][j] = (f32x4){0.f, 0.f, 0.f, 0.f};

  // A staging (proven): slot row = tid>>3, chunk = tid&7, source pre-swizzle
  const int sm = tid >> 3, su = tid & 7;
  const int sx = (su ^ (sm & 7)) * 8;
  const u16* a_src[4];
  #pragma unroll
  for (int i = 0; i < 4; ++i) a_src[i] = embn + (size_t)(sm + i * 64) * ND + sx;

  // B staging: thread -> (col pair nc2, k-oct ko = wave id)
  const int nc2 = (lane) * 2;            // local cols nc2, nc2+1
  const int ko = w;                      // k-oct 0..7 (8 rows each)
  int gc2 = cblk + nc2;
  if (gc2 > NC - 2) gc2 = NC - 2;        // clamp; masked in epilogue
  const int n0 = nc2, n1 = nc2 + 1;
  u16* bdst0 = Bs + n0 * 64 + (ko ^ bswz(n0)) * 8;
  u16* bdst1 = Bs + n1 * 64 + (ko ^ bswz(n1)) * 8;
  float ssa = 0.f, ssb = 0.f;

  for (int ks = 0; ks < 8; ++ks) {
    const int k0 = ks * 64;
    // B: 8 x float2 at consecutive k-rows (512B/wave segments)
    float2 f[8];
    #pragma unroll
    for (int i = 0; i < 8; ++i)
      f[i] = *(const float2*)(kern + (size_t)(k0 + ko * 8 + i) * NC + gc2);
    // A: 4 x global_load_lds(16B)
    #pragma unroll
    for (int i = 0; i < 4; ++i) gload16(a_src[i] + k0, &As[i * 4096 + w * 512]);
    // B: in-register transpose + convert + ssq + 2 x b128 LDS writes
    u16x8 q0, q1;
    #pragma unroll
    for (int i = 0; i < 8; ++i) {
      ssa += f[i].x * f[i].x; ssb += f[i].y * f[i].y;
      q0[i] = f2bf(f[i].x);   q1[i] = f2bf(f[i].y);
    }
    *(u16x8*)bdst0 = q0;
    *(u16x8*)bdst1 = q1;
    __syncthreads();                       // tiles ready
    #pragma unroll
    for (int kf = 0; kf < 2; ++kf) {
      bf16x8 bfr[4], afr[4];
      #pragma unroll
      for (int nf = 0; nf < 4; ++nf) {
        const int n = nbase + nf * 16 + l15;
        bfr[nf] = *(const bf16x8*)(Bs + n * 64 + (((kf * 4 + g) ^ bswz(n)) * 8));
      }
      #pragma unroll
      for (int mf = 0; mf < 4; ++mf) {
        const int m = mbase + mf * 16 + l15;
        afr[mf] = *(const bf16x8*)(As + m * 64 + ((kf * 32 + g * 8) ^ ((m & 7) << 3)));
      }
      #pragma unroll
      for (int mf = 0; mf < 4; ++mf)
        #pragma unroll
        for (int nf = 0; nf < 4; ++nf)
          acc[mf][nf] = __builtin_amdgcn_mfma_f32_16x16x32_bf16(afr[mf], bfr[nf], acc[mf][nf], 0, 0, 0);
    }
    __syncthreads();                       // protect LDS before re-stage
  }

  // column ssq partials + deterministic reduce (8 k-octs -> 1)
  colp[ko][n0] = ssa; colp[ko][n1] = ssb;
  __syncthreads();
  if (tid < 128) {
    float s = ((colp[0][tid] + colp[1][tid]) + (colp[2][tid] + colp[3][tid]))
            + ((colp[4][tid] + colp[5][tid]) + (colp[6][tid] + colp[7][tid]));
    colp[0][tid] = s;
  }
  __syncthreads();

  // ---- fused epilogue: stats straight from accumulators ----
  float cinv[4];
  #pragma unroll
  for (int nf = 0; nf < 4; ++nf) {
    const int nl = nbase + nf * 16 + l15;
    cinv[nf] = ((cblk + nl) < NC) ? (1.0f / sqrtf(colp[0][nl])) : 0.f;
  }
  u32 cnt_t = 0;
  #pragma unroll
  for (int mf = 0; mf < 4; ++mf) {
    #pragma unroll
    for (int r = 0; r < 4; ++r) {
      const int row = mbase + mf * 16 + g * 4 + r;
      const float tg = tgtws[row];
      const int lb = lab[row];
      float e = 0.f; u64 pk = 0ull;
      #pragma unroll
      for (int nf = 0; nf < 4; ++nf) {
        const int c = cblk + nbase + nf * 16 + l15;
        if (c < NC) {
          float v = acc[mf][nf][r] * cinv[nf];
          v = fminf(fmaxf(v, -1.0f), 1.0f);
          e += exp2f(EXP2K * v);
          const u64 pq = ((u64)ordkey(v) << 32) | (u32)(0xFFFFFFFFu - (u32)c);
          if (pq > pk) pk = pq;
          if (c != lb) {
            if (v > tg) cnt_t++;
            else if (v >= THRC) {
              u32 pos = atomicAdd(&scal[1], 1u);
              if (pos < CAP) buf[pos] = ((u64)ordkey(v) << 32) | (u32)row;
            }
          }
        }
      }
      #pragma unroll
      for (int m = 1; m < 16; m <<= 1) {
        e += __shfl_xor(e, m, 64);
        u64 o = __shfl_xor(pk, m, 64);
        if (o > pk) pk = o;
      }
      if (l15 == 0) {
        sexp_pair[w & 1][row] = e;          // each (w&1,row) written exactly once
        atomicMax(&amax_lds[row], pk);      // integer max: order-independent
      }
    }
  }
  #pragma unroll
  for (int m = 1; m < 64; m <<= 1) cnt_t += __shfl_xor(cnt_t, m, 64);
  if (lane == 0) swcnt[w] = cnt_t;
  __syncthreads();
  if (tid == 0) {
    u32 s = 0;
    #pragma unroll
    for (int i = 0; i < 8; ++i) s += swcnt[i];
    atomicAdd(&scal[0], s);
  }
  if (tid < 256) {
    sexp_part[(size_t)tid * 800 + p] = sexp_pair[0][tid] + sexp_pair[1][tid];
    atomicMax(&amax_g[tid], amax_lds[tid]);
  }
}

// ---------------- K3: deterministic per-row sexp reduction ------------
__global__ void k_reduce(const float* __restrict__ part, float* __restrict__ sexpws) {
  __shared__ float s[256];
  const int r = blockIdx.x, t = threadIdx.x;
  float a = 0.f;
  for (int b = t; b < NBLK; b += 256) a += part[(size_t)r * 800 + b];
  s[t] = a;
  __syncthreads();
  for (int st = 128; st > 0; st >>= 1) { if (t < st) s[t] += s[t + st]; __syncthreads(); }
  if (t == 0) sexpws[r] = s[0];
}

// ---------------- K4: finisher (1 block): select th + stats + loss ----
__global__ __launch_bounds__(1024) void k_finish(const u64* __restrict__ buf,
                                                 const u32* __restrict__ scal,
                                                 const int* __restrict__ lab,
                                                 const float* __restrict__ tgtws,
                                                 const float* __restrict__ sexpws,
                                                 const u64* __restrict__ amax_g,
                                                 float* __restrict__ out) {
  __shared__ u32 hist[4096];
  __shared__ u32 s[1024], cs[1024];
  __shared__ u32 sb1, sr1, sb2, sr2, sthkey, lcnt;
  __shared__ u64 lbuf[512];
  __shared__ float rl[256], ra[256];
  const int tid = threadIdx.x;
  const int n = (int)min(scal[1], (u32)CAP);
  const int topk = (int)scal[0];
  int a = 25599744 - topk; if (a < 0) a = 0;               // B*(C-1)
  int k = (int)ceilf((1.0f / 99999.0f) * (float)a);        // mirror ref f32 math
  if (k < 1) k = 1;

  if (tid == 0) { sb1 = 0; sr1 = 1; sb2 = 0; sr2 = 1; lcnt = 0; }
  // ---- level 1: key bits 31..20 ----
  for (int i = tid; i < 4096; i += 1024) hist[i] = 0;
  __syncthreads();
  for (int i = tid; i < n; i += 1024) atomicAdd(&hist[(u32)(buf[i] >> 52)], 1u);
  __syncthreads();
  {
    u32 h[4]; u32 c = 0;
    #pragma unroll
    for (int j = 0; j < 4; ++j) { h[j] = hist[tid * 4 + j]; c += h[j]; }
    cs[tid] = c; s[tid] = c;
    __syncthreads();
    for (int off = 1; off < 1024; off <<= 1) {
      u32 v = (tid + off < 1024) ? s[tid + off] : 0u;
      __syncthreads(); s[tid] += v; __syncthreads();
    }
    u32 incl = s[tid], excl = incl - cs[tid];
    if ((int)excl < k && (int)incl >= k) {
      u32 cum = excl;
      for (int j = 3; j >= 0; --j) {
        cum += h[j];
        if ((int)cum >= k) { sb1 = tid * 4 + j; sr1 = (u32)k - (cum - h[j]); break; }
      }
    }
  }
  __syncthreads();
  const u32 b1 = sb1, r1 = sr1;
  // ---- level 2: key bits 19..8 ----
  for (int i = tid; i < 4096; i += 1024) hist[i] = 0;
  __syncthreads();
  for (int i = tid; i < n; i += 1024) {
    u32 key = (u32)(buf[i] >> 32);
    if ((key >> 20) == b1) atomicAdd(&hist[(key >> 8) & 4095u], 1u);
  }
  __syncthreads();
  {
    u32 h[4]; u32 c = 0;
    #pragma unroll
    for (int j = 0; j < 4; ++j) { h[j] = hist[tid * 4 + j]; c += h[j]; }
    cs[tid] = c; s[tid] = c;
    __syncthreads();
    for (int off = 1; off < 1024; off <<= 1) {
      u32 v = (tid + off < 1024) ? s[tid + off] : 0u;
      __syncthreads(); s[tid] += v; __syncthreads();
    }
    u32 incl = s[tid], excl = incl - cs[tid];
    if (excl < r1 && incl >= r1) {
      u32 cum = excl;
      for (int j = 3; j >= 0; --j) {
        cum += h[j];
        if (cum >= r1) { sb2 = tid * 4 + j; sr2 = r1 - (cum - h[j]); break; }
      }
    }
  }
  __syncthreads();
  const u32 b2 = sb2, r2 = sr2;
  // ---- level 3: key bits 7..0 ----
  for (int i = tid; i < 256; i += 1024) hist[i] = 0;
  __syncthreads();
  const u32 pfx = (b1 << 12) | b2;
  for (int i = tid; i < n; i += 1024) {
    u32 key = (u32)(buf[i] >> 32);
    if ((key >> 8) == pfx) atomicAdd(&hist[key & 255u], 1u);
  }
  __syncthreads();
  if (tid == 0) {
    u32 cum = 0, b3 = 0;
    for (int j = 255; j >= 0; --j) { cum += hist[j]; if (cum >= r2) { b3 = (u32)j; break; } }
    sthkey = (b1 << 20) | (b2 << 8) | b3;
  }
  __syncthreads();
  const u32 thk = sthkey;
  // ---- collect strictly-greater entries (k-1 < 512 of them) ----
  for (int i = tid; i < n; i += 1024) {
    u64 e = buf[i];
    if ((u32)(e >> 32) > thk) { u32 pq = atomicAdd(&lcnt, 1u); if (pq < 512) lbuf[pq] = e; }
  }
  __syncthreads();
  const int m = (int)min(lcnt, 512u);
  if (tid < 256) {
    const int r = tid;
    int cnt = 0; float ssq = 0.f;
    for (int j = 0; j < m; ++j) {
      u64 e = lbuf[j];
      if ((u32)(e & 0xFFFFFFFFu) == (u32)r) {
        float v = inv_ordkey((u32)(e >> 32));
        cnt++; ssq += v * v;
      }
    }
    const float tg = tgtws[r];
    const float times = fmaxf((float)cnt, 1.0f);
    const float nm = ssq / times;
    const float tgm = (tg - 0.4f) - (1.0f + tg) * nm;
    const float sexp = sexpws[r] - exp2f(EXP2K * tg) + exp2f(EXP2K * tgm);
    rl[r] = logf(sexp) - 64.0f * tgm;
    const u32 acol = 0xFFFFFFFFu - (u32)(amax_g[r] & 0xFFFFFFFFu);
    ra[r] = (acol == (u32)lab[r]) ? 1.0f : 0.0f;
  }
  __syncthreads();
  for (int st = 128; st > 0; st >>= 1) {
    if (tid < st) { rl[tid] += rl[tid + st]; ra[tid] += ra[tid + st]; }
    __syncthreads();
  }
  if (tid == 0) { out[0] = rl[0] * (1.0f / 256.0f); out[1] = ra[0] * (1.0f / 256.0f); }
}

extern "C" void kernel_launch(void* const* d_in, const int* in_sizes, int n_in,
                              void* d_out, int out_size, void* d_ws, size_t ws_size,
                              hipStream_t stream) {
  const float* emb = (const float*)d_in[0];
  const int* lab = (const int*)d_in[1];
  const float* kern = (const float*)d_in[2];
  float* out = (float*)d_out;
  char* ws = (char*)d_ws;

  u16* embn = (u16*)(ws + OFF_EMBN);
  float* tgtws = (float*)(ws + OFF_TGT);
  float* sexpws = (float*)(ws + OFF_SEXP);
  u64* amax_g = (u64*)(ws + OFF_AMAX);
  u32* scal = (u32*)(ws + OFF_SCAL);   // [0]=topk [1]=bufcnt
  float* part = (float*)(ws + OFF_PART);
  u64* buf = (u64*)(ws + OFF_BUF);

  k_prep<<<NB, 128, 0, stream>>>(emb, embn, amax_g, scal);
  k_tgt<<<NB, 512, 0, stream>>>(kern, embn, lab, tgtws);
  k_gemm<<<NBLK, 512, 0, stream>>>(kern, embn, lab, tgtws, scal, buf, amax_g, part);
  k_reduce<<<NB, 256, 0, stream>>>(part, sexpws);
  k_finish<<<1, 1024, 0, stream>>>(buf, scal, lab, tgtws, sexpws, amax_g, out);
}